// Round 13
// baseline (99.974 us; speedup 1.0000x reference)
//
#include <hip/hip_runtime.h>
#include <hip/hip_bf16.h>

typedef float  f32x4  __attribute__((ext_vector_type(4)));
typedef float  f32x16 __attribute__((ext_vector_type(16)));
typedef short  short8 __attribute__((ext_vector_type(8)));
typedef int    i32x2  __attribute__((ext_vector_type(2)));
typedef unsigned int uint4v __attribute__((ext_vector_type(4)));

#define N_  2
#define L_  4096
#define S_  4096
#define H_  8
#define D_  64
#define HD_ 512        // H_*D_
#define KVB 64
#define QB  64         // q-rows per block (all 4 waves share them)
#define NSL 32         // 32-s slices per wave (S/4/32)

// fp32 -> bf16 (round-nearest-even), manual
__device__ __forceinline__ unsigned short f2bf(float f) {
  unsigned int u = __builtin_bit_cast(unsigned int, f);
  u += 0x7fffu + ((u >> 16) & 1u);
  return (unsigned short)(u >> 16);
}
__device__ __forceinline__ unsigned short bf16c(float f) {
  return __builtin_bit_cast(unsigned short, __float2bfloat16(f));
}
// v_cvt_pk_bf16_f32 (no builtin on gfx950)
__device__ __forceinline__ unsigned int pk2(float lo, float hi) {
  unsigned int r;
  asm("v_cvt_pk_bf16_f32 %0, %1, %2" : "=v"(r) : "v"(lo), "v"(hi));
  return r;
}
__device__ __forceinline__ f32x16 zero16() {
  f32x16 v;
  #pragma unroll
  for (int i = 0; i < 16; ++i) v[i] = 0.f;
  return v;
}
__device__ __forceinline__ float tsum16(const f32x16& v) {
  float a0 = v[0] + v[1],   a1 = v[2] + v[3];
  float a2 = v[4] + v[5],   a3 = v[6] + v[7];
  float a4 = v[8] + v[9],   a5 = v[10] + v[11];
  float a6 = v[12] + v[13], a7 = v[14] + v[15];
  float b0 = a0 + a1, b1 = a2 + a3, b2 = a4 + a5, b3 = a6 + a7;
  return (b0 + b1) + (b2 + b3);
}

// ---------------------------------------------------------------------------
// Pre-pass: K,V fp32 -> bf16 fragment-contiguous tile images (direct-VMEM).
// K image (per nh,t): elem = (d>>3)*512 + s*8 + (d&7)
// V image (per nh,t): elem = (s>>3)*512 + d*8 + (s&7)
// ---------------------------------------------------------------------------
__global__ __launch_bounds__(256, 8)
void prepack(const float* __restrict__ Kg, const float* __restrict__ Vg,
             unsigned short* __restrict__ Kw, unsigned short* __restrict__ Vw) {
  const int b = blockIdx.x;             // 0..2047
  const int tid = threadIdx.x;
  const int isV = (b >= 1024);
  const int tb = isV ? b - 1024 : b;    // (nh, t) tile id
  const int nh = tb >> 6, t = tb & 63;
  const int n = nh >> 3, h = nh & 7;

  if (!isV) {
    const int sl = tid >> 2, d0 = (tid & 3) << 4;
    const float* src = Kg + ((size_t)(n * S_ + t * 64 + sl) * H_ + h) * D_ + d0;
    f32x4 x0 = *(const f32x4*)(src);
    f32x4 x1 = *(const f32x4*)(src + 4);
    f32x4 x2 = *(const f32x4*)(src + 8);
    f32x4 x3 = *(const f32x4*)(src + 12);
    short8 t0, t1;
    t0[0] = (short)f2bf(x0[0]); t0[1] = (short)f2bf(x0[1]);
    t0[2] = (short)f2bf(x0[2]); t0[3] = (short)f2bf(x0[3]);
    t0[4] = (short)f2bf(x1[0]); t0[5] = (short)f2bf(x1[1]);
    t0[6] = (short)f2bf(x1[2]); t0[7] = (short)f2bf(x1[3]);
    t1[0] = (short)f2bf(x2[0]); t1[1] = (short)f2bf(x2[1]);
    t1[2] = (short)f2bf(x2[2]); t1[3] = (short)f2bf(x2[3]);
    t1[4] = (short)f2bf(x3[0]); t1[5] = (short)f2bf(x3[1]);
    t1[6] = (short)f2bf(x3[2]); t1[7] = (short)f2bf(x3[3]);
    unsigned short* dst = Kw + (size_t)tb * 4096;
    const int b0 = d0 >> 3;
    *(short8*)&dst[(b0)     * 512 + sl * 8] = t0;
    *(short8*)&dst[(b0 + 1) * 512 + sl * 8] = t1;
  } else {
    const int d = tid & 63, sb2 = tid >> 6;
    #pragma unroll
    for (int c = 0; c < 2; ++c) {
      const int sblk = sb2 * 2 + c;
      const float* src = Vg + ((size_t)(n * S_ + t * 64 + sblk * 8) * H_ + h) * D_ + d;
      short8 o;
      #pragma unroll
      for (int j = 0; j < 8; ++j) o[j] = (short)f2bf(src[(size_t)j * HD_]);
      *(short8*)&Vw[(size_t)tb * 4096 + sblk * 512 + d * 8] = o;
    }
  }
}

// build pa0/pa1 (A-frags for s-chunks 0-15 / 16-31) from a 16-score vector
__device__ __forceinline__ void mk_pa(const f32x16& s, short8& pa0, short8& pa1) {
  {
    const unsigned int c0 = pk2(s[0], s[1]);
    const unsigned int c1 = pk2(s[2], s[3]);
    const unsigned int c2 = pk2(s[4], s[5]);
    const unsigned int c3 = pk2(s[6], s[7]);
    i32x2 r0 = __builtin_amdgcn_permlane32_swap((int)c0, (int)c2, false, false);
    i32x2 r1 = __builtin_amdgcn_permlane32_swap((int)c1, (int)c3, false, false);
    uint4v w = { (unsigned)r0[0], (unsigned)r1[0], (unsigned)r0[1], (unsigned)r1[1] };
    pa0 = __builtin_bit_cast(short8, w);
  }
  {
    const unsigned int c0 = pk2(s[8],  s[9]);
    const unsigned int c1 = pk2(s[10], s[11]);
    const unsigned int c2 = pk2(s[12], s[13]);
    const unsigned int c3 = pk2(s[14], s[15]);
    i32x2 r0 = __builtin_amdgcn_permlane32_swap((int)c0, (int)c2, false, false);
    i32x2 r1 = __builtin_amdgcn_permlane32_swap((int)c1, (int)c3, false, false);
    uint4v w = { (unsigned)r0[0], (unsigned)r1[0], (unsigned)r0[1], (unsigned)r1[1] };
    pa1 = __builtin_bit_cast(short8, w);
  }
}

// ---------------------------------------------------------------------------
// Slice body: 64 q-rows/wave (q-blocks A,B) x one 32-s slice. 8 loads feed
// 16 MFMA. NO inline-asm waits / sched_barriers (r12 finding: compiler
// tracks plain register loads exactly and schedules across phases).
// Slice stride = 16384 B (4 interleaved waves cover consecutive slices).
// ---------------------------------------------------------------------------
template<int DOK, int DOV>
__device__ __forceinline__ void slice_body(
    int i, const char* kbase, const char* vbase,
    const short8 qfA[4], const short8 qfB[4], short8 kf[4], short8 vf[4],
    f32x16& accA0, f32x16& accA1, f32x16& accB0, f32x16& accB1,
    float& lsumA, float& lsumB)
{
  f32x16 sA = zero16(), sB = zero16();
  __builtin_amdgcn_s_setprio(1);
  #pragma unroll
  for (int kc = 0; kc < 4; ++kc)
    sA = __builtin_amdgcn_mfma_f32_32x32x16_bf16(kf[kc], qfA[kc], sA, 0, 0, 0);
  #pragma unroll
  for (int kc = 0; kc < 4; ++kc)
    sB = __builtin_amdgcn_mfma_f32_32x32x16_bf16(kf[kc], qfB[kc], sB, 0, 0, 0);
  __builtin_amdgcn_s_setprio(0);

  if (DOK) {  // prefetch kf[i+1] (compiler renames regs -> auto double-buffer)
    const char* kp = kbase + (size_t)(i + 1) * 16384;
    #pragma unroll
    for (int kc = 0; kc < 4; ++kc)
      kf[kc] = *(const short8*)(kp + kc * 2048);
  }

  #pragma unroll
  for (int r = 0; r < 16; ++r) sA[r] = __builtin_amdgcn_exp2f(sA[r]);
  lsumA += tsum16(sA);
  #pragma unroll
  for (int r = 0; r < 16; ++r) sB[r] = __builtin_amdgcn_exp2f(sB[r]);
  lsumB += tsum16(sB);

  short8 paA0, paA1, paB0, paB1;
  mk_pa(sA, paA0, paA1);
  __builtin_amdgcn_s_setprio(1);
  accA0 = __builtin_amdgcn_mfma_f32_32x32x16_bf16(paA0, vf[0], accA0, 0, 0, 0);
  accA1 = __builtin_amdgcn_mfma_f32_32x32x16_bf16(paA0, vf[1], accA1, 0, 0, 0);
  accA0 = __builtin_amdgcn_mfma_f32_32x32x16_bf16(paA1, vf[2], accA0, 0, 0, 0);
  accA1 = __builtin_amdgcn_mfma_f32_32x32x16_bf16(paA1, vf[3], accA1, 0, 0, 0);
  __builtin_amdgcn_s_setprio(0);
  mk_pa(sB, paB0, paB1);
  __builtin_amdgcn_s_setprio(1);
  accB0 = __builtin_amdgcn_mfma_f32_32x32x16_bf16(paB0, vf[0], accB0, 0, 0, 0);
  accB1 = __builtin_amdgcn_mfma_f32_32x32x16_bf16(paB0, vf[1], accB1, 0, 0, 0);
  accB0 = __builtin_amdgcn_mfma_f32_32x32x16_bf16(paB1, vf[2], accB0, 0, 0, 0);
  accB1 = __builtin_amdgcn_mfma_f32_32x32x16_bf16(paB1, vf[3], accB1, 0, 0, 0);
  __builtin_amdgcn_s_setprio(0);

  if (DOV) {  // prefetch vf[i+1]
    const char* vp = vbase + (size_t)(i + 1) * 16384;
    #pragma unroll
    for (int q4 = 0; q4 < 4; ++q4)
      vf[q4] = *(const short8*)(vp + (q4 >> 1) * 2048 + (q4 & 1) * 512);
  }
}

// ---------------------------------------------------------------------------
// 256-thread blocks: 4 waves, ONE q-group of 64 rows shared by all, s split
// 4 ways in interleaved 32-s slices (same 16KB tile stream -> L1 dedup).
// Grid 1024 = 4 blocks/CU = 4 waves/SIMD of INDEPENDENT (non-barriered)
// work + free compiler scheduling: the untested combination from r11/r12.
// __launch_bounds__(256,2): empirical hipcc rule = VGPR cap 256/arg = 128.
// Residency comes from the grid (4 x 96-120 VGPR <= 512 pool, 17KB x 4 LDS).
// ---------------------------------------------------------------------------
__global__ __launch_bounds__(256, 2)
void attn_fa10(const float* __restrict__ Qg,
               const unsigned short* __restrict__ Kw,
               const unsigned short* __restrict__ Vw,
               float* __restrict__ Og) {
  __shared__ __align__(16) float Comb[QB * 64];   // 16 KiB (epilogue only)
  __shared__ float CombL[QB];                     // 256 B

  const int tid = threadIdx.x;
  const int sh  = tid >> 6;       // s-quarter 0..3
  const int ln  = tid & 63;
  const int hi  = ln >> 5;
  const int c32 = ln & 31;

  const int bid = blockIdx.x;                    // 1024 blocks
  const int swz = (bid & 7) * 128 + (bid >> 3);  // XCD-contiguous
  const int qt  = swz & 63;                      // 64 q-tiles of 64 rows
  const int nh  = swz >> 6;                      // 2 nh per XCD -> K/V L2-resident
  const int h = nh & 7, n = nh >> 3;
  const int qbase = qt * QB;

  // ---- Q fragments for both q-blocks, scaled by 1/sqrt(D)*log2(e) ----
  const float qs = 0.125f * 1.44269504088896340736f;
  short8 qfA[4], qfB[4];
  #pragma unroll
  for (int b = 0; b < 2; ++b) {
    const int qrow = qbase + b * 32 + c32;
    const float* qp = Qg + (size_t)(n * L_ + qrow) * HD_ + h * D_ + (hi << 3);
    #pragma unroll
    for (int kc = 0; kc < 4; ++kc) {
      const float* p = qp + (kc << 4);
      f32x4 a = *(const f32x4*)(p);
      f32x4 bx = *(const f32x4*)(p + 4);
      short8 f;
      f[0] = (short)bf16c(a[0] * qs);  f[1] = (short)bf16c(a[1] * qs);
      f[2] = (short)bf16c(a[2] * qs);  f[3] = (short)bf16c(a[3] * qs);
      f[4] = (short)bf16c(bx[0] * qs); f[5] = (short)bf16c(bx[1] * qs);
      f[6] = (short)bf16c(bx[2] * qs); f[7] = (short)bf16c(bx[3] * qs);
      if (b == 0) qfA[kc] = f; else qfB[kc] = f;
    }
  }

  f32x16 accA0 = zero16(), accA1 = zero16(), accB0 = zero16(), accB1 = zero16();
  float lsumA = 0.f, lsumB = 0.f;

  // wave sh handles slices u = 4*i + sh (i = 0..31)
  const char* kbase = (const char*)(Kw + (size_t)nh * 64 * 4096)
                      + ((sh >> 1) * 8192) + ((sh & 1) * 512)
                      + (hi << 10) + (c32 << 4);
  const char* vbase = (const char*)(Vw + (size_t)nh * 64 * 4096)
                      + ((sh >> 1) * 8192) + ((sh & 1) * 4096)
                      + (hi << 10) + (c32 << 4);

  short8 kf[4], vf[4];
  #pragma unroll
  for (int kc = 0; kc < 4; ++kc)
    kf[kc] = *(const short8*)(kbase + kc * 2048);
  #pragma unroll
  for (int q4 = 0; q4 < 4; ++q4)
    vf[q4] = *(const short8*)(vbase + (q4 >> 1) * 2048 + (q4 & 1) * 512);

  for (int i = 0; i < NSL - 1; ++i)
    slice_body<1, 1>(i, kbase, vbase, qfA, qfB, kf, vf,
                     accA0, accA1, accB0, accB1, lsumA, lsumB);
  slice_body<0, 0>(NSL - 1, kbase, vbase, qfA, qfB, kf, vf,
                   accA0, accA1, accB0, accB1, lsumA, lsumB);

  // ---- epilogue: 4-way combine through LDS (3 add phases), then store ----
  const float fullA = lsumA + __shfl_xor(lsumA, 32);   // row sum, q = c32
  const float fullB = lsumB + __shfl_xor(lsumB, 32);   // row sum, q = 32+c32

  if (sh == 3) {
    #pragma unroll
    for (int r = 0; r < 16; ++r) {
      const int q = (r & 3) + 8 * (r >> 2) + 4 * hi;
      Comb[q * 64 + c32]             = accA0[r];
      Comb[q * 64 + 32 + c32]        = accA1[r];
      Comb[(32 + q) * 64 + c32]      = accB0[r];
      Comb[(32 + q) * 64 + 32 + c32] = accB1[r];
    }
    if (hi == 0) { CombL[c32] = fullA; CombL[32 + c32] = fullB; }
  }
  __syncthreads();
  if (sh == 2) {
    #pragma unroll
    for (int r = 0; r < 16; ++r) {
      const int q = (r & 3) + 8 * (r >> 2) + 4 * hi;
      Comb[q * 64 + c32]             += accA0[r];
      Comb[q * 64 + 32 + c32]        += accA1[r];
      Comb[(32 + q) * 64 + c32]      += accB0[r];
      Comb[(32 + q) * 64 + 32 + c32] += accB1[r];
    }
    if (hi == 0) { CombL[c32] += fullA; CombL[32 + c32] += fullB; }
  }
  __syncthreads();
  if (sh == 1) {
    #pragma unroll
    for (int r = 0; r < 16; ++r) {
      const int q = (r & 3) + 8 * (r >> 2) + 4 * hi;
      Comb[q * 64 + c32]             += accA0[r];
      Comb[q * 64 + 32 + c32]        += accA1[r];
      Comb[(32 + q) * 64 + c32]      += accB0[r];
      Comb[(32 + q) * 64 + 32 + c32] += accB1[r];
    }
    if (hi == 0) { CombL[c32] += fullA; CombL[32 + c32] += fullB; }
  }
  __syncthreads();
  if (sh == 0) {
    const float ltotA = fullA + CombL[c32];
    const float ltotB = fullB + CombL[32 + c32];
    #pragma unroll
    for (int r = 0; r < 16; ++r) {
      const int q = (r & 3) + 8 * (r >> 2) + 4 * hi;
      const float lA = __shfl(ltotA, q);
      const float lB = __shfl(ltotB, q);
      float* opA = Og + (size_t)(n * L_ + qbase + q) * HD_ + h * D_ + c32;
      float* opB = Og + (size_t)(n * L_ + qbase + 32 + q) * HD_ + h * D_ + c32;
      opA[0]  = (accA0[r] + Comb[q * 64 + c32])             / lA;
      opA[32] = (accA1[r] + Comb[q * 64 + 32 + c32])        / lA;
      opB[0]  = (accB0[r] + Comb[(32 + q) * 64 + c32])      / lB;
      opB[32] = (accB1[r] + Comb[(32 + q) * 64 + 32 + c32]) / lB;
    }
  }
}

extern "C" void kernel_launch(void* const* d_in, const int* in_sizes, int n_in,
                              void* d_out, int out_size, void* d_ws, size_t ws_size,
                              hipStream_t stream) {
  (void)in_sizes; (void)n_in; (void)out_size; (void)ws_size;
  const float* Q = (const float*)d_in[0];
  const float* K = (const float*)d_in[1];
  const float* V = (const float*)d_in[2];
  float* O = (float*)d_out;

  unsigned short* Kw = (unsigned short*)d_ws;            // 8 MiB
  unsigned short* Vw = Kw + 4194304;                     // 8 MiB (ws >= 16 MiB verified)
  hipLaunchKernelGGL(prepack, dim3(2048), dim3(256), 0, stream, K, V, Kw, Vw);
  hipLaunchKernelGGL(attn_fa10, dim3(1024), dim3(256), 0, stream, Q, Kw, Vw, O);
}

// Round 14
// 97.905 us; speedup vs baseline: 1.0211x; 1.0211x over previous
//
#include <hip/hip_runtime.h>
#include <hip/hip_bf16.h>

typedef float  f32x4  __attribute__((ext_vector_type(4)));
typedef float  f32x16 __attribute__((ext_vector_type(16)));
typedef short  short8 __attribute__((ext_vector_type(8)));
typedef int    i32x2  __attribute__((ext_vector_type(2)));
typedef unsigned int uint4v __attribute__((ext_vector_type(4)));

#define N_  2
#define L_  4096
#define S_  4096
#define H_  8
#define D_  64
#define HD_ 512        // H_*D_
#define KVB 64
#define QB  128        // q-rows per block (2 q-waves x 64)
#define NT  64         // S/KVB tiles; each wave does its 32-s half of every tile

// fp32 -> bf16 (round-nearest-even), manual
__device__ __forceinline__ unsigned short f2bf(float f) {
  unsigned int u = __builtin_bit_cast(unsigned int, f);
  u += 0x7fffu + ((u >> 16) & 1u);
  return (unsigned short)(u >> 16);
}
__device__ __forceinline__ unsigned short bf16c(float f) {
  return __builtin_bit_cast(unsigned short, __float2bfloat16(f));
}
// v_cvt_pk_bf16_f32 (no builtin on gfx950)
__device__ __forceinline__ unsigned int pk2(float lo, float hi) {
  unsigned int r;
  asm("v_cvt_pk_bf16_f32 %0, %1, %2" : "=v"(r) : "v"(lo), "v"(hi));
  return r;
}
__device__ __forceinline__ f32x16 zero16() {
  f32x16 v;
  #pragma unroll
  for (int i = 0; i < 16; ++i) v[i] = 0.f;
  return v;
}
__device__ __forceinline__ float tsum16(const f32x16& v) {
  float a0 = v[0] + v[1],   a1 = v[2] + v[3];
  float a2 = v[4] + v[5],   a3 = v[6] + v[7];
  float a4 = v[8] + v[9],   a5 = v[10] + v[11];
  float a6 = v[12] + v[13], a7 = v[14] + v[15];
  float b0 = a0 + a1, b1 = a2 + a3, b2 = a4 + a5, b3 = a6 + a7;
  return (b0 + b1) + (b2 + b3);
}

// ---------------------------------------------------------------------------
// Pre-pass: K,V fp32 -> bf16 fragment-contiguous tile images (direct-VMEM).
// K image (per nh,t): elem = (d>>3)*512 + s*8 + (d&7)
// V image (per nh,t): elem = (s>>3)*512 + d*8 + (s&7)
// ---------------------------------------------------------------------------
__global__ __launch_bounds__(256, 8)
void prepack(const float* __restrict__ Kg, const float* __restrict__ Vg,
             unsigned short* __restrict__ Kw, unsigned short* __restrict__ Vw) {
  const int b = blockIdx.x;             // 0..2047
  const int tid = threadIdx.x;
  const int isV = (b >= 1024);
  const int tb = isV ? b - 1024 : b;    // (nh, t) tile id
  const int nh = tb >> 6, t = tb & 63;
  const int n = nh >> 3, h = nh & 7;

  if (!isV) {
    const int sl = tid >> 2, d0 = (tid & 3) << 4;
    const float* src = Kg + ((size_t)(n * S_ + t * 64 + sl) * H_ + h) * D_ + d0;
    f32x4 x0 = *(const f32x4*)(src);
    f32x4 x1 = *(const f32x4*)(src + 4);
    f32x4 x2 = *(const f32x4*)(src + 8);
    f32x4 x3 = *(const f32x4*)(src + 12);
    short8 t0, t1;
    t0[0] = (short)f2bf(x0[0]); t0[1] = (short)f2bf(x0[1]);
    t0[2] = (short)f2bf(x0[2]); t0[3] = (short)f2bf(x0[3]);
    t0[4] = (short)f2bf(x1[0]); t0[5] = (short)f2bf(x1[1]);
    t0[6] = (short)f2bf(x1[2]); t0[7] = (short)f2bf(x1[3]);
    t1[0] = (short)f2bf(x2[0]); t1[1] = (short)f2bf(x2[1]);
    t1[2] = (short)f2bf(x2[2]); t1[3] = (short)f2bf(x2[3]);
    t1[4] = (short)f2bf(x3[0]); t1[5] = (short)f2bf(x3[1]);
    t1[6] = (short)f2bf(x3[2]); t1[7] = (short)f2bf(x3[3]);
    unsigned short* dst = Kw + (size_t)tb * 4096;
    const int b0 = d0 >> 3;
    *(short8*)&dst[(b0)     * 512 + sl * 8] = t0;
    *(short8*)&dst[(b0 + 1) * 512 + sl * 8] = t1;
  } else {
    const int d = tid & 63, sb2 = tid >> 6;
    #pragma unroll
    for (int c = 0; c < 2; ++c) {
      const int sblk = sb2 * 2 + c;
      const float* src = Vg + ((size_t)(n * S_ + t * 64 + sblk * 8) * H_ + h) * D_ + d;
      short8 o;
      #pragma unroll
      for (int j = 0; j < 8; ++j) o[j] = (short)f2bf(src[(size_t)j * HD_]);
      *(short8*)&Vw[(size_t)tb * 4096 + sblk * 512 + d * 8] = o;
    }
  }
}

// build pa0/pa1 (A-frags for s-chunks 0-15 / 16-31) from a 16-score vector
__device__ __forceinline__ void mk_pa(const f32x16& s, short8& pa0, short8& pa1) {
  {
    const unsigned int c0 = pk2(s[0], s[1]);
    const unsigned int c1 = pk2(s[2], s[3]);
    const unsigned int c2 = pk2(s[4], s[5]);
    const unsigned int c3 = pk2(s[6], s[7]);
    i32x2 r0 = __builtin_amdgcn_permlane32_swap((int)c0, (int)c2, false, false);
    i32x2 r1 = __builtin_amdgcn_permlane32_swap((int)c1, (int)c3, false, false);
    uint4v w = { (unsigned)r0[0], (unsigned)r1[0], (unsigned)r0[1], (unsigned)r1[1] };
    pa0 = __builtin_bit_cast(short8, w);
  }
  {
    const unsigned int c0 = pk2(s[8],  s[9]);
    const unsigned int c1 = pk2(s[10], s[11]);
    const unsigned int c2 = pk2(s[12], s[13]);
    const unsigned int c3 = pk2(s[14], s[15]);
    i32x2 r0 = __builtin_amdgcn_permlane32_swap((int)c0, (int)c2, false, false);
    i32x2 r1 = __builtin_amdgcn_permlane32_swap((int)c1, (int)c3, false, false);
    uint4v w = { (unsigned)r0[0], (unsigned)r1[0], (unsigned)r0[1], (unsigned)r1[1] };
    pa1 = __builtin_bit_cast(short8, w);
  }
}

// ---------------------------------------------------------------------------
// Tile body: 64 q-rows/wave (2 q-blocks A,B), 32-s slice of each 64-s tile.
// 8 loads feed 16 MFMA. No inline-asm waits, NO s_setprio (r13 ablation:
// every multi-wave variant since r2 wrapped MFMA in setprio(1); per-slice
// wall fits N_waves x serial-chain exactly => waves never overlapped. prio-1
// MFMA regions starve co-resident waves' trans/VALU issue -- the T5
// prerequisite (phase-diverse barrier schedule) does not hold here, and
// m190 measured setprio NEGATIVE on non-phase-locked multi-wave GEMM.)
// ---------------------------------------------------------------------------
template<int DOK, int DOV>
__device__ __forceinline__ void tile_body(
    int t, const char* kbase, const char* vbase,
    const short8 qfA[4], const short8 qfB[4], short8 kf[4], short8 vf[4],
    f32x16& accA0, f32x16& accA1, f32x16& accB0, f32x16& accB1,
    float& lsumA, float& lsumB)
{
  f32x16 sA = zero16(), sB = zero16();
  #pragma unroll
  for (int kc = 0; kc < 4; ++kc)
    sA = __builtin_amdgcn_mfma_f32_32x32x16_bf16(kf[kc], qfA[kc], sA, 0, 0, 0);
  #pragma unroll
  for (int kc = 0; kc < 4; ++kc)
    sB = __builtin_amdgcn_mfma_f32_32x32x16_bf16(kf[kc], qfB[kc], sB, 0, 0, 0);

  if (DOK) {  // prefetch kf[t+1] (compiler renames regs -> auto double-buffer)
    const char* kp = kbase + (size_t)(t + 1) * 8192;
    #pragma unroll
    for (int kc = 0; kc < 4; ++kc)
      kf[kc] = *(const short8*)(kp + kc * 2048);
  }

  #pragma unroll
  for (int r = 0; r < 16; ++r) sA[r] = __builtin_amdgcn_exp2f(sA[r]);
  lsumA += tsum16(sA);
  #pragma unroll
  for (int r = 0; r < 16; ++r) sB[r] = __builtin_amdgcn_exp2f(sB[r]);
  lsumB += tsum16(sB);

  short8 paA0, paA1, paB0, paB1;
  mk_pa(sA, paA0, paA1);
  accA0 = __builtin_amdgcn_mfma_f32_32x32x16_bf16(paA0, vf[0], accA0, 0, 0, 0);
  accA1 = __builtin_amdgcn_mfma_f32_32x32x16_bf16(paA0, vf[1], accA1, 0, 0, 0);
  accA0 = __builtin_amdgcn_mfma_f32_32x32x16_bf16(paA1, vf[2], accA0, 0, 0, 0);
  accA1 = __builtin_amdgcn_mfma_f32_32x32x16_bf16(paA1, vf[3], accA1, 0, 0, 0);
  mk_pa(sB, paB0, paB1);
  accB0 = __builtin_amdgcn_mfma_f32_32x32x16_bf16(paB0, vf[0], accB0, 0, 0, 0);
  accB1 = __builtin_amdgcn_mfma_f32_32x32x16_bf16(paB0, vf[1], accB1, 0, 0, 0);
  accB0 = __builtin_amdgcn_mfma_f32_32x32x16_bf16(paB1, vf[2], accB0, 0, 0, 0);
  accB1 = __builtin_amdgcn_mfma_f32_32x32x16_bf16(paB1, vf[3], accB1, 0, 0, 0);

  if (DOV) {  // prefetch vf[t+1]
    const char* vp = vbase + (size_t)(t + 1) * 8192;
    #pragma unroll
    for (int q4 = 0; q4 < 4; ++q4)
      vf[q4] = *(const short8*)(vp + (q4 >> 1) * 2048 + (q4 & 1) * 512);
  }
}

// ---------------------------------------------------------------------------
// 256-thread blocks: 2 q-waves(64q each) x 2 s-halves (split WITHIN each tile
// so all 4 waves share one 16KB tile stream -> L1 dedup). Barrier-free loop.
// __launch_bounds__(256,2): empirical hipcc rule = VGPR cap 256/arg = 128.
// ---------------------------------------------------------------------------
__global__ __launch_bounds__(256, 2)
void attn_fa11(const float* __restrict__ Qg,
               const unsigned short* __restrict__ Kw,
               const unsigned short* __restrict__ Vw,
               float* __restrict__ Og) {
  __shared__ __align__(16) float Comb[2][4096];   // 32 KiB (epilogue only)
  __shared__ float CombL[2][64];                  // 512 B

  const int tid = threadIdx.x;
  const int wv  = tid >> 6;       // 0..3
  const int qw  = wv & 1;         // q-wave (64 q each)
  const int sh  = wv >> 1;        // s-half within each tile
  const int ln  = tid & 63;
  const int hi  = ln >> 5;
  const int c32 = ln & 31;

  const int bid = blockIdx.x;
  const int swz = (bid & 7) * 64 + (bid >> 3);   // XCD-contiguous
  const int qt  = swz & 31;
  const int nh  = swz >> 5;                      // 2 nh per XCD -> K/V L2-resident
  const int h = nh & 7, n = nh >> 3;
  const int qbase = qt * QB + qw * 64;

  // ---- Q fragments for both q-blocks, scaled by 1/sqrt(D)*log2(e) ----
  const float qs = 0.125f * 1.44269504088896340736f;
  short8 qfA[4], qfB[4];
  #pragma unroll
  for (int b = 0; b < 2; ++b) {
    const int qrow = qbase + b * 32 + c32;
    const float* qp = Qg + (size_t)(n * L_ + qrow) * HD_ + h * D_ + (hi << 3);
    #pragma unroll
    for (int kc = 0; kc < 4; ++kc) {
      const float* p = qp + (kc << 4);
      f32x4 a = *(const f32x4*)(p);
      f32x4 bx = *(const f32x4*)(p + 4);
      short8 f;
      f[0] = (short)bf16c(a[0] * qs);  f[1] = (short)bf16c(a[1] * qs);
      f[2] = (short)bf16c(a[2] * qs);  f[3] = (short)bf16c(a[3] * qs);
      f[4] = (short)bf16c(bx[0] * qs); f[5] = (short)bf16c(bx[1] * qs);
      f[6] = (short)bf16c(bx[2] * qs); f[7] = (short)bf16c(bx[3] * qs);
      if (b == 0) qfA[kc] = f; else qfB[kc] = f;
    }
  }

  f32x16 accA0 = zero16(), accA1 = zero16(), accB0 = zero16(), accB1 = zero16();
  float lsumA = 0.f, lsumB = 0.f;

  // per-lane global bases; s-slice = [sh*32, sh*32+32) of every tile
  const char* kbase = (const char*)(Kw + (size_t)nh * 64 * 4096)
                      + (hi << 10) + (sh << 9) + (c32 << 4);
  const char* vbase = (const char*)(Vw + (size_t)nh * 64 * 4096)
                      + (sh << 12) + (hi << 10) + (c32 << 4);

  short8 kf[4], vf[4];
  #pragma unroll
  for (int kc = 0; kc < 4; ++kc)
    kf[kc] = *(const short8*)(kbase + kc * 2048);
  #pragma unroll
  for (int q4 = 0; q4 < 4; ++q4)
    vf[q4] = *(const short8*)(vbase + (q4 >> 1) * 2048 + (q4 & 1) * 512);

  for (int t = 0; t < NT - 1; ++t)
    tile_body<1, 1>(t, kbase, vbase, qfA, qfB, kf, vf,
                    accA0, accA1, accB0, accB1, lsumA, lsumB);
  tile_body<0, 0>(NT - 1, kbase, vbase, qfA, qfB, kf, vf,
                  accA0, accA1, accB0, accB1, lsumA, lsumB);

  // ---- epilogue: combine the two s-halves through LDS, normalize, store ----
  const float fullA = lsumA + __shfl_xor(lsumA, 32);   // row sum, q = c32
  const float fullB = lsumB + __shfl_xor(lsumB, 32);   // row sum, q = 32+c32
  float* C = &Comb[qw][0];                             // 64q x 64d

  if (sh == 1) {
    #pragma unroll
    for (int r = 0; r < 16; ++r) {
      const int q = (r & 3) + 8 * (r >> 2) + 4 * hi;
      C[q * 64 + c32]             = accA0[r];
      C[q * 64 + 32 + c32]        = accA1[r];
      C[(32 + q) * 64 + c32]      = accB0[r];
      C[(32 + q) * 64 + 32 + c32] = accB1[r];
    }
    if (hi == 0) { CombL[qw][c32] = fullA; CombL[qw][32 + c32] = fullB; }
  }
  __syncthreads();
  if (sh == 0) {
    const float ltotA = fullA + CombL[qw][c32];
    const float ltotB = fullB + CombL[qw][32 + c32];
    #pragma unroll
    for (int r = 0; r < 16; ++r) {
      const int q = (r & 3) + 8 * (r >> 2) + 4 * hi;
      const float lA = __shfl(ltotA, q);
      const float lB = __shfl(ltotB, q);
      const int rowA = qbase + q;
      const int rowB = qbase + 32 + q;
      float* opA = Og + (size_t)(n * L_ + rowA) * HD_ + h * D_ + c32;
      float* opB = Og + (size_t)(n * L_ + rowB) * HD_ + h * D_ + c32;
      opA[0]  = (accA0[r] + C[q * 64 + c32])             / lA;
      opA[32] = (accA1[r] + C[q * 64 + 32 + c32])        / lA;
      opB[0]  = (accB0[r] + C[(32 + q) * 64 + c32])      / lB;
      opB[32] = (accB1[r] + C[(32 + q) * 64 + 32 + c32]) / lB;
    }
  }
}

extern "C" void kernel_launch(void* const* d_in, const int* in_sizes, int n_in,
                              void* d_out, int out_size, void* d_ws, size_t ws_size,
                              hipStream_t stream) {
  (void)in_sizes; (void)n_in; (void)out_size; (void)ws_size;
  const float* Q = (const float*)d_in[0];
  const float* K = (const float*)d_in[1];
  const float* V = (const float*)d_in[2];
  float* O = (float*)d_out;

  unsigned short* Kw = (unsigned short*)d_ws;            // 8 MiB
  unsigned short* Vw = Kw + 4194304;                     // 8 MiB (ws >= 16 MiB verified)
  hipLaunchKernelGGL(prepack, dim3(2048), dim3(256), 0, stream, K, V, Kw, Vw);
  hipLaunchKernelGGL(attn_fa11, dim3(512), dim3(256), 0, stream, Q, Kw, Vw, O);
}

// Round 15
// 93.538 us; speedup vs baseline: 1.0688x; 1.0467x over previous
//
#include <hip/hip_runtime.h>
#include <hip/hip_bf16.h>

typedef float  f32x4  __attribute__((ext_vector_type(4)));
typedef float  f32x16 __attribute__((ext_vector_type(16)));
typedef short  short8 __attribute__((ext_vector_type(8)));
typedef int    i32x2  __attribute__((ext_vector_type(2)));
typedef unsigned int uint4v __attribute__((ext_vector_type(4)));

#define N_  2
#define L_  4096
#define S_  4096
#define H_  8
#define D_  64
#define HD_ 512        // H_*D_
#define KVB 64
#define QB  128        // q-rows per block (2 q-waves x 64)
#define NT  64         // S/KVB tiles; each wave does its 32-s half of every tile

// fp32 -> bf16 (round-nearest-even), manual
__device__ __forceinline__ unsigned short f2bf(float f) {
  unsigned int u = __builtin_bit_cast(unsigned int, f);
  u += 0x7fffu + ((u >> 16) & 1u);
  return (unsigned short)(u >> 16);
}
__device__ __forceinline__ unsigned short bf16c(float f) {
  return __builtin_bit_cast(unsigned short, __float2bfloat16(f));
}
// v_cvt_pk_bf16_f32 (no builtin on gfx950)
__device__ __forceinline__ unsigned int pk2(float lo, float hi) {
  unsigned int r;
  asm("v_cvt_pk_bf16_f32 %0, %1, %2" : "=v"(r) : "v"(lo), "v"(hi));
  return r;
}
__device__ __forceinline__ f32x16 zero16() {
  f32x16 v;
  #pragma unroll
  for (int i = 0; i < 16; ++i) v[i] = 0.f;
  return v;
}
__device__ __forceinline__ float tsum16(const f32x16& v) {
  float a0 = v[0] + v[1],   a1 = v[2] + v[3];
  float a2 = v[4] + v[5],   a3 = v[6] + v[7];
  float a4 = v[8] + v[9],   a5 = v[10] + v[11];
  float a6 = v[12] + v[13], a7 = v[14] + v[15];
  float b0 = a0 + a1, b1 = a2 + a3, b2 = a4 + a5, b3 = a6 + a7;
  return (b0 + b1) + (b2 + b3);
}

// ---------------------------------------------------------------------------
// Pre-pass: K,V fp32 -> bf16 fragment-contiguous tile images (direct-VMEM).
// K image (per nh,t): elem = (d>>3)*512 + s*8 + (d&7)
// V image (per nh,t): elem = (s>>3)*512 + d*8 + (s&7)
// ---------------------------------------------------------------------------
__global__ __launch_bounds__(256, 8)
void prepack(const float* __restrict__ Kg, const float* __restrict__ Vg,
             unsigned short* __restrict__ Kw, unsigned short* __restrict__ Vw) {
  const int b = blockIdx.x;             // 0..2047
  const int tid = threadIdx.x;
  const int isV = (b >= 1024);
  const int tb = isV ? b - 1024 : b;    // (nh, t) tile id
  const int nh = tb >> 6, t = tb & 63;
  const int n = nh >> 3, h = nh & 7;

  if (!isV) {
    const int sl = tid >> 2, d0 = (tid & 3) << 4;
    const float* src = Kg + ((size_t)(n * S_ + t * 64 + sl) * H_ + h) * D_ + d0;
    f32x4 x0 = *(const f32x4*)(src);
    f32x4 x1 = *(const f32x4*)(src + 4);
    f32x4 x2 = *(const f32x4*)(src + 8);
    f32x4 x3 = *(const f32x4*)(src + 12);
    short8 t0, t1;
    t0[0] = (short)f2bf(x0[0]); t0[1] = (short)f2bf(x0[1]);
    t0[2] = (short)f2bf(x0[2]); t0[3] = (short)f2bf(x0[3]);
    t0[4] = (short)f2bf(x1[0]); t0[5] = (short)f2bf(x1[1]);
    t0[6] = (short)f2bf(x1[2]); t0[7] = (short)f2bf(x1[3]);
    t1[0] = (short)f2bf(x2[0]); t1[1] = (short)f2bf(x2[1]);
    t1[2] = (short)f2bf(x2[2]); t1[3] = (short)f2bf(x2[3]);
    t1[4] = (short)f2bf(x3[0]); t1[5] = (short)f2bf(x3[1]);
    t1[6] = (short)f2bf(x3[2]); t1[7] = (short)f2bf(x3[3]);
    unsigned short* dst = Kw + (size_t)tb * 4096;
    const int b0 = d0 >> 3;
    *(short8*)&dst[(b0)     * 512 + sl * 8] = t0;
    *(short8*)&dst[(b0 + 1) * 512 + sl * 8] = t1;
  } else {
    const int d = tid & 63, sb2 = tid >> 6;
    #pragma unroll
    for (int c = 0; c < 2; ++c) {
      const int sblk = sb2 * 2 + c;
      const float* src = Vg + ((size_t)(n * S_ + t * 64 + sblk * 8) * H_ + h) * D_ + d;
      short8 o;
      #pragma unroll
      for (int j = 0; j < 8; ++j) o[j] = (short)f2bf(src[(size_t)j * HD_]);
      *(short8*)&Vw[(size_t)tb * 4096 + sblk * 512 + d * 8] = o;
    }
  }
}

// build pa0/pa1 (A-frags for s-chunks 0-15 / 16-31) from a 16-score vector
__device__ __forceinline__ void mk_pa(const f32x16& s, short8& pa0, short8& pa1) {
  {
    const unsigned int c0 = pk2(s[0], s[1]);
    const unsigned int c1 = pk2(s[2], s[3]);
    const unsigned int c2 = pk2(s[4], s[5]);
    const unsigned int c3 = pk2(s[6], s[7]);
    i32x2 r0 = __builtin_amdgcn_permlane32_swap((int)c0, (int)c2, false, false);
    i32x2 r1 = __builtin_amdgcn_permlane32_swap((int)c1, (int)c3, false, false);
    uint4v w = { (unsigned)r0[0], (unsigned)r1[0], (unsigned)r0[1], (unsigned)r1[1] };
    pa0 = __builtin_bit_cast(short8, w);
  }
  {
    const unsigned int c0 = pk2(s[8],  s[9]);
    const unsigned int c1 = pk2(s[10], s[11]);
    const unsigned int c2 = pk2(s[12], s[13]);
    const unsigned int c3 = pk2(s[14], s[15]);
    i32x2 r0 = __builtin_amdgcn_permlane32_swap((int)c0, (int)c2, false, false);
    i32x2 r1 = __builtin_amdgcn_permlane32_swap((int)c1, (int)c3, false, false);
    uint4v w = { (unsigned)r0[0], (unsigned)r1[0], (unsigned)r0[1], (unsigned)r1[1] };
    pa1 = __builtin_bit_cast(short8, w);
  }
}

// ---------------------------------------------------------------------------
// Tile body: 64 q-rows/wave (2 q-blocks A,B), 32-s slice of tile tt; next
// tile ttn prefetched. 8 loads feed 16 MFMA. No inline-asm waits (compiler
// tracks plain register loads exactly).
// ---------------------------------------------------------------------------
template<int DOK, int DOV>
__device__ __forceinline__ void tile_body(
    int ttn, const char* kbase, const char* vbase,
    const short8 qfA[4], const short8 qfB[4], short8 kf[4], short8 vf[4],
    f32x16& accA0, f32x16& accA1, f32x16& accB0, f32x16& accB1,
    float& lsumA, float& lsumB)
{
  f32x16 sA = zero16(), sB = zero16();
  __builtin_amdgcn_s_setprio(1);
  #pragma unroll
  for (int kc = 0; kc < 4; ++kc)
    sA = __builtin_amdgcn_mfma_f32_32x32x16_bf16(kf[kc], qfA[kc], sA, 0, 0, 0);
  #pragma unroll
  for (int kc = 0; kc < 4; ++kc)
    sB = __builtin_amdgcn_mfma_f32_32x32x16_bf16(kf[kc], qfB[kc], sB, 0, 0, 0);
  __builtin_amdgcn_s_setprio(0);

  if (DOK) {  // prefetch kf[ttn] (compiler renames regs -> auto double-buffer)
    const char* kp = kbase + (size_t)ttn * 8192;
    #pragma unroll
    for (int kc = 0; kc < 4; ++kc)
      kf[kc] = *(const short8*)(kp + kc * 2048);
  }

  #pragma unroll
  for (int r = 0; r < 16; ++r) sA[r] = __builtin_amdgcn_exp2f(sA[r]);
  lsumA += tsum16(sA);
  #pragma unroll
  for (int r = 0; r < 16; ++r) sB[r] = __builtin_amdgcn_exp2f(sB[r]);
  lsumB += tsum16(sB);

  short8 paA0, paA1, paB0, paB1;
  mk_pa(sA, paA0, paA1);
  __builtin_amdgcn_s_setprio(1);
  accA0 = __builtin_amdgcn_mfma_f32_32x32x16_bf16(paA0, vf[0], accA0, 0, 0, 0);
  accA1 = __builtin_amdgcn_mfma_f32_32x32x16_bf16(paA0, vf[1], accA1, 0, 0, 0);
  accA0 = __builtin_amdgcn_mfma_f32_32x32x16_bf16(paA1, vf[2], accA0, 0, 0, 0);
  accA1 = __builtin_amdgcn_mfma_f32_32x32x16_bf16(paA1, vf[3], accA1, 0, 0, 0);
  __builtin_amdgcn_s_setprio(0);
  mk_pa(sB, paB0, paB1);
  __builtin_amdgcn_s_setprio(1);
  accB0 = __builtin_amdgcn_mfma_f32_32x32x16_bf16(paB0, vf[0], accB0, 0, 0, 0);
  accB1 = __builtin_amdgcn_mfma_f32_32x32x16_bf16(paB0, vf[1], accB1, 0, 0, 0);
  accB0 = __builtin_amdgcn_mfma_f32_32x32x16_bf16(paB1, vf[2], accB0, 0, 0, 0);
  accB1 = __builtin_amdgcn_mfma_f32_32x32x16_bf16(paB1, vf[3], accB1, 0, 0, 0);
  __builtin_amdgcn_s_setprio(0);

  if (DOV) {  // prefetch vf[ttn]
    const char* vp = vbase + (size_t)ttn * 8192;
    #pragma unroll
    for (int q4 = 0; q4 < 4; ++q4)
      vf[q4] = *(const short8*)(vp + (q4 >> 1) * 2048 + (q4 & 1) * 512);
  }
}

// ---------------------------------------------------------------------------
// 256-thread blocks: 2 q-waves(64q each) x 2 s-halves. Barrier-free loop.
// NEW (r14): block-parity tile ROTATION -- block p=(bid>>3)&1 visits tiles
// (t + 32p) & 63. The two co-resident blocks on a CU previously streamed
// IDENTICAL K/V addresses; L1 hits ratchet a lagging wave forward until
// lockstep -> all waves phase-locked -> MFMA/VALU/trans pipes serialize
// (wall == sum of pipes, measured r4-r13). Disjoint streams break the
// ratchet so co-resident waves drift into different phases and overlap.
// __launch_bounds__(256,2): empirical hipcc rule = VGPR cap 256/arg = 128.
// ---------------------------------------------------------------------------
__global__ __launch_bounds__(256, 2)
void attn_fa12(const float* __restrict__ Qg,
               const unsigned short* __restrict__ Kw,
               const unsigned short* __restrict__ Vw,
               float* __restrict__ Og) {
  __shared__ __align__(16) float Comb[2][4096];   // 32 KiB (epilogue only)
  __shared__ float CombL[2][64];                  // 512 B

  const int tid = threadIdx.x;
  const int wv  = tid >> 6;       // 0..3
  const int qw  = wv & 1;         // q-wave (64 q each)
  const int sh  = wv >> 1;        // s-half within each tile
  const int ln  = tid & 63;
  const int hi  = ln >> 5;
  const int c32 = ln & 31;

  const int bid = blockIdx.x;
  const int swz = (bid & 7) * 64 + (bid >> 3);   // XCD-contiguous
  const int qt  = swz & 31;
  const int nh  = swz >> 5;                      // 2 nh per XCD -> K/V L2-resident
  const int p   = (bid >> 3) & 1;                // co-resident-block parity
  const int h = nh & 7, n = nh >> 3;
  const int qbase = qt * QB + qw * 64;

  // ---- Q fragments for both q-blocks, scaled by 1/sqrt(D)*log2(e) ----
  const float qs = 0.125f * 1.44269504088896340736f;
  short8 qfA[4], qfB[4];
  #pragma unroll
  for (int b = 0; b < 2; ++b) {
    const int qrow = qbase + b * 32 + c32;
    const float* qp = Qg + (size_t)(n * L_ + qrow) * HD_ + h * D_ + (hi << 3);
    #pragma unroll
    for (int kc = 0; kc < 4; ++kc) {
      const float* pp = qp + (kc << 4);
      f32x4 a = *(const f32x4*)(pp);
      f32x4 bx = *(const f32x4*)(pp + 4);
      short8 f;
      f[0] = (short)bf16c(a[0] * qs);  f[1] = (short)bf16c(a[1] * qs);
      f[2] = (short)bf16c(a[2] * qs);  f[3] = (short)bf16c(a[3] * qs);
      f[4] = (short)bf16c(bx[0] * qs); f[5] = (short)bf16c(bx[1] * qs);
      f[6] = (short)bf16c(bx[2] * qs); f[7] = (short)bf16c(bx[3] * qs);
      if (b == 0) qfA[kc] = f; else qfB[kc] = f;
    }
  }

  f32x16 accA0 = zero16(), accA1 = zero16(), accB0 = zero16(), accB1 = zero16();
  float lsumA = 0.f, lsumB = 0.f;

  // per-lane global bases; s-slice = [sh*32, sh*32+32) of every tile
  const char* kbase = (const char*)(Kw + (size_t)nh * 64 * 4096)
                      + (hi << 10) + (sh << 9) + (c32 << 4);
  const char* vbase = (const char*)(Vw + (size_t)nh * 64 * 4096)
                      + (sh << 12) + (hi << 10) + (c32 << 4);

  short8 kf[4], vf[4];
  int tt = p << 5;                  // start tile: 0 or 32 per block parity
  {
    const char* kp = kbase + (size_t)tt * 8192;
    #pragma unroll
    for (int kc = 0; kc < 4; ++kc)
      kf[kc] = *(const short8*)(kp + kc * 2048);
    const char* vp = vbase + (size_t)tt * 8192;
    #pragma unroll
    for (int q4 = 0; q4 < 4; ++q4)
      vf[q4] = *(const short8*)(vp + (q4 >> 1) * 2048 + (q4 & 1) * 512);
  }

  for (int t = 0; t < NT - 1; ++t) {
    const int ttn = (tt + 1) & 63;
    tile_body<1, 1>(ttn, kbase, vbase, qfA, qfB, kf, vf,
                    accA0, accA1, accB0, accB1, lsumA, lsumB);
    tt = ttn;
  }
  tile_body<0, 0>(0, kbase, vbase, qfA, qfB, kf, vf,
                  accA0, accA1, accB0, accB1, lsumA, lsumB);

  // ---- epilogue: combine the two s-halves through LDS, normalize, store ----
  const float fullA = lsumA + __shfl_xor(lsumA, 32);   // row sum, q = c32
  const float fullB = lsumB + __shfl_xor(lsumB, 32);   // row sum, q = 32+c32
  float* C = &Comb[qw][0];                             // 64q x 64d

  if (sh == 1) {
    #pragma unroll
    for (int r = 0; r < 16; ++r) {
      const int q = (r & 3) + 8 * (r >> 2) + 4 * hi;
      C[q * 64 + c32]             = accA0[r];
      C[q * 64 + 32 + c32]        = accA1[r];
      C[(32 + q) * 64 + c32]      = accB0[r];
      C[(32 + q) * 64 + 32 + c32] = accB1[r];
    }
    if (hi == 0) { CombL[qw][c32] = fullA; CombL[qw][32 + c32] = fullB; }
  }
  __syncthreads();
  if (sh == 0) {
    const float ltotA = fullA + CombL[qw][c32];
    const float ltotB = fullB + CombL[qw][32 + c32];
    #pragma unroll
    for (int r = 0; r < 16; ++r) {
      const int q = (r & 3) + 8 * (r >> 2) + 4 * hi;
      const float lA = __shfl(ltotA, q);
      const float lB = __shfl(ltotB, q);
      const int rowA = qbase + q;
      const int rowB = qbase + 32 + q;
      float* opA = Og + (size_t)(n * L_ + rowA) * HD_ + h * D_ + c32;
      float* opB = Og + (size_t)(n * L_ + rowB) * HD_ + h * D_ + c32;
      opA[0]  = (accA0[r] + C[q * 64 + c32])             / lA;
      opA[32] = (accA1[r] + C[q * 64 + 32 + c32])        / lA;
      opB[0]  = (accB0[r] + C[(32 + q) * 64 + c32])      / lB;
      opB[32] = (accB1[r] + C[(32 + q) * 64 + 32 + c32]) / lB;
    }
  }
}

extern "C" void kernel_launch(void* const* d_in, const int* in_sizes, int n_in,
                              void* d_out, int out_size, void* d_ws, size_t ws_size,
                              hipStream_t stream) {
  (void)in_sizes; (void)n_in; (void)out_size; (void)ws_size;
  const float* Q = (const float*)d_in[0];
  const float* K = (const float*)d_in[1];
  const float* V = (const float*)d_in[2];
  float* O = (float*)d_out;

  unsigned short* Kw = (unsigned short*)d_ws;            // 8 MiB
  unsigned short* Vw = Kw + 4194304;                     // 8 MiB (ws >= 16 MiB verified)
  hipLaunchKernelGGL(prepack, dim3(2048), dim3(256), 0, stream, K, V, Kw, Vw);
  hipLaunchKernelGGL(attn_fa12, dim3(512), dim3(256), 0, stream, Q, Kw, Vw, O);
}